// Round 1
// baseline (1277.272 us; speedup 1.0000x reference)
//
#include <hip/hip_runtime.h>

#define HH 256
#define WW 256
#define CIN 64
#define NPIX 65536  // HH*WW

__device__ __forceinline__ int refl(int t, int n) {
    // reflection padding of 1: -1 -> 1, n -> n-2
    if (t < 0) return -t;
    if (t >= n) return 2 * n - 2 - t;
    return t;
}

// ---------------------------------------------------------------------------
// Kernel 1: compute softmax attention weights w9[n][9][H][W]
// tile 32x32 (+1 halo for x2), 256 threads
// ---------------------------------------------------------------------------
__global__ __launch_bounds__(256)
void san_weights(const float* __restrict__ x,
                 const float* __restrict__ w1, const float* __restrict__ b1,
                 const float* __restrict__ w2, const float* __restrict__ b2,
                 const float* __restrict__ cpw,
                 const float* __restrict__ bn1g, const float* __restrict__ bn1b,
                 const float* __restrict__ bn1m, const float* __restrict__ bn1v,
                 const float* __restrict__ wmid,
                 const float* __restrict__ bn2g, const float* __restrict__ bn2b,
                 const float* __restrict__ bn2m, const float* __restrict__ bn2v,
                 const float* __restrict__ wout, const float* __restrict__ bout,
                 float* __restrict__ w9)
{
    __shared__ float ls[16 * 1156];  // ch 0..7 = x1, ch 8..15 = x2, 34x34 cells
    const int n = blockIdx.z;
    const int ty = blockIdx.y * 32, tx = blockIdx.x * 32;
    const int tid = threadIdx.x;
    const float* xn = x + (size_t)n * CIN * NPIX;

    // ---- phase 1: x1 and x2 over the 34x34 halo region ----
    for (int cell = tid; cell < 1156; cell += 256) {
        int ly = cell / 34, lx = cell - ly * 34;
        int gy = refl(ty + ly - 1, HH);
        int gx = refl(tx + lx - 1, WW);
        const float* xp = xn + gy * WW + gx;
        float xv[64];
        #pragma unroll
        for (int c = 0; c < CIN; ++c) xv[c] = xp[(size_t)c * NPIX];
        #pragma unroll
        for (int o = 0; o < 16; ++o) {
            const float* wp = (o < 8) ? (w1 + o * CIN) : (w2 + (o - 8) * CIN);
            float a = (o < 8) ? b1[o] : b2[o - 8];
            #pragma unroll
            for (int c = 0; c < CIN; ++c) a = fmaf(wp[c], xv[c], a);
            ls[o * 1156 + cell] = a;
        }
    }
    __syncthreads();

    // ---- fold BN params (uniform, cheap) ----
    float s1[10], o1[10];
    #pragma unroll
    for (int c = 0; c < 10; ++c) {
        float s = bn1g[c] * rsqrtf(bn1v[c] + 1e-5f);
        s1[c] = s;
        o1[c] = bn1b[c] - bn1m[c] * s;
    }
    float s2[8], o2[8];
    #pragma unroll
    for (int e = 0; e < 8; ++e) {
        float s = bn2g[e] * rsqrtf(bn2v[e] + 1e-5f);
        s2[e] = s;
        o2[e] = bn2b[e] - bn2m[e] * s;
    }
    const float cp00 = cpw[0], cp01 = cpw[1], cp10 = cpw[2], cp11 = cpw[3];
    const float bo = bout[0];

    // ---- phase 2: MLP + softmax per tile pixel ----
    for (int i = tid; i < 1024; i += 256) {
        int py = i >> 5, px = i & 31;
        int h = ty + py, w = tx + px;
        int cell = (py + 1) * 34 + (px + 1);
        float x1v[8];
        #pragma unroll
        for (int c = 0; c < 8; ++c) x1v[c] = ls[c * 1156 + cell];
        float lg[9];
        #pragma unroll
        for (int k = 0; k < 9; ++k) {
            int dy = k / 3 - 1, dx = k % 3 - 1;
            int nc = cell + dy * 34 + dx;
            float f[10];
            #pragma unroll
            for (int c = 0; c < 8; ++c) f[c] = x1v[c] - ls[(8 + c) * 1156 + nc];
            int hn = refl(h + dy, HH), wn = refl(w + dx, WW);
            float dp0 = (2.0f / 255.0f) * (float)(w - wn);
            float dp1 = (2.0f / 255.0f) * (float)(h - hn);
            f[8] = cp00 * dp0 + cp01 * dp1;
            f[9] = cp10 * dp0 + cp11 * dp1;
            float a[10];
            #pragma unroll
            for (int c = 0; c < 10; ++c)
                a[c] = fmaxf(fmaf(f[c], s1[c], o1[c]), 0.0f);
            float lgk = bo;
            #pragma unroll
            for (int e = 0; e < 8; ++e) {
                float g = 0.0f;
                #pragma unroll
                for (int c = 0; c < 10; ++c) g = fmaf(wmid[e * 10 + c], a[c], g);
                g = fmaxf(fmaf(g, s2[e], o2[e]), 0.0f);
                lgk = fmaf(wout[e], g, lgk);
            }
            lg[k] = lgk;
        }
        float m = lg[0];
        #pragma unroll
        for (int k = 1; k < 9; ++k) m = fmaxf(m, lg[k]);
        float e9[9], ssum = 0.0f;
        #pragma unroll
        for (int k = 0; k < 9; ++k) { e9[k] = __expf(lg[k] - m); ssum += e9[k]; }
        float inv = 1.0f / ssum;
        size_t base = (size_t)n * 9 * NPIX + h * WW + w;
        #pragma unroll
        for (int k = 0; k < 9; ++k) w9[base + (size_t)k * NPIX] = e9[k] * inv;
    }
}

// ---------------------------------------------------------------------------
// Kernel 2: s_c = sum_k w_k * x_c[p+dk]  then  out = W3 @ s + b3
// tile 32x32, 1024 threads (1 px/thread), x staged in 16-channel LDS chunks
// ---------------------------------------------------------------------------
__global__ __launch_bounds__(1024)
void san_agg(const float* __restrict__ x, const float* __restrict__ w9,
             const float* __restrict__ w3, const float* __restrict__ b3,
             float* __restrict__ out)
{
    __shared__ float ls[16 * 1156];
    const int n = blockIdx.z;
    const int ty = blockIdx.y * 32, tx = blockIdx.x * 32;
    const int tid = threadIdx.x;
    const int px = tid & 31, py = tid >> 5;
    const int h = ty + py, w = tx + px;
    const float* xn = x + (size_t)n * CIN * NPIX;

    float wk[9];
    {
        size_t base = (size_t)n * 9 * NPIX + h * WW + w;
        #pragma unroll
        for (int k = 0; k < 9; ++k) wk[k] = w9[base + (size_t)k * NPIX];
    }
    float acc[64];
    #pragma unroll
    for (int o = 0; o < 64; ++o) acc[o] = 0.0f;

    const int cellc = (py + 1) * 34 + (px + 1);
    for (int c0 = 0; c0 < 64; c0 += 16) {
        __syncthreads();
        for (int idx = tid; idx < 16 * 1156; idx += 1024) {
            int cc = idx / 1156, cell = idx - cc * 1156;
            int ly = cell / 34, lx = cell - ly * 34;
            int gy = refl(ty + ly - 1, HH), gx = refl(tx + lx - 1, WW);
            ls[idx] = xn[(size_t)(c0 + cc) * NPIX + gy * WW + gx];
        }
        __syncthreads();
        float sv[16];
        #pragma unroll
        for (int cc = 0; cc < 16; ++cc) {
            const float* pl = ls + cc * 1156 + cellc;
            float s = wk[0] * pl[-35];
            s = fmaf(wk[1], pl[-34], s);
            s = fmaf(wk[2], pl[-33], s);
            s = fmaf(wk[3], pl[-1],  s);
            s = fmaf(wk[4], pl[0],   s);
            s = fmaf(wk[5], pl[1],   s);
            s = fmaf(wk[6], pl[33],  s);
            s = fmaf(wk[7], pl[34],  s);
            s = fmaf(wk[8], pl[35],  s);
            sv[cc] = s;
        }
        #pragma unroll
        for (int o = 0; o < 64; ++o) {
            #pragma unroll
            for (int cc = 0; cc < 16; ++cc)
                acc[o] = fmaf(w3[o * CIN + c0 + cc], sv[cc], acc[o]);
        }
    }
    size_t ob = (size_t)n * CIN * NPIX + h * WW + w;
    #pragma unroll
    for (int o = 0; o < 64; ++o)
        out[ob + (size_t)o * NPIX] = acc[o] + b3[o];
}

// ---------------------------------------------------------------------------
extern "C" void kernel_launch(void* const* d_in, const int* in_sizes, int n_in,
                              void* d_out, int out_size, void* d_ws, size_t ws_size,
                              hipStream_t stream) {
    const float* x      = (const float*)d_in[0];
    const float* w1     = (const float*)d_in[1];
    const float* b1     = (const float*)d_in[2];
    const float* w2     = (const float*)d_in[3];
    const float* b2     = (const float*)d_in[4];
    const float* w3     = (const float*)d_in[5];
    const float* b3     = (const float*)d_in[6];
    const float* cpw    = (const float*)d_in[7];
    const float* cpb    = (const float*)d_in[8];  // cancels in pd (p - p_shift)
    const float* bn1g   = (const float*)d_in[9];
    const float* bn1b   = (const float*)d_in[10];
    const float* bn1m   = (const float*)d_in[11];
    const float* bn1v   = (const float*)d_in[12];
    const float* wmid   = (const float*)d_in[13];
    const float* bn2g   = (const float*)d_in[14];
    const float* bn2b   = (const float*)d_in[15];
    const float* bn2m   = (const float*)d_in[16];
    const float* bn2v   = (const float*)d_in[17];
    const float* wout   = (const float*)d_in[18];
    const float* bout   = (const float*)d_in[19];
    (void)cpb;
    float* out = (float*)d_out;
    float* w9  = (float*)d_ws;  // 16*9*65536 floats = 37.75 MB

    dim3 grid(8, 8, 16);
    san_weights<<<grid, 256, 0, stream>>>(x, w1, b1, w2, b2, cpw,
                                          bn1g, bn1b, bn1m, bn1v, wmid,
                                          bn2g, bn2b, bn2m, bn2v, wout, bout, w9);
    san_agg<<<grid, 1024, 0, stream>>>(x, w9, w3, b3, out);
}

// Round 2
// 800.823 us; speedup vs baseline: 1.5950x; 1.5950x over previous
//
#include <hip/hip_runtime.h>
#include <stdint.h>

#define HH 256
#define WW 256
#define CIN 64
#define NPIX 65536
#define TW 64
#define TH 16
#define NCELL 1188    // 66*18 halo cells
#define NCELLP 1216   // padded to multiple of 64

typedef uint32_t u32;

__device__ __forceinline__ int refl(int t, int n) {
    if (t < 0) return -t;
    if (t >= n) return 2 * n - 2 - t;
    return t;
}

__device__ __forceinline__ void gload_lds4(const float* g, float* l) {
    __builtin_amdgcn_global_load_lds(
        (const __attribute__((address_space(1))) u32*)g,
        (__attribute__((address_space(3))) u32*)l, 4, 0, 0);
}

__device__ __forceinline__ u32 bfpack(float a, float b) {
    u32 ua = __float_as_uint(a), ub = __float_as_uint(b);
    ua = (ua + 0x7fffu + ((ua >> 16) & 1u)) >> 16;
    ub = (ub + 0x7fffu + ((ub >> 16) & 1u)) & 0xffff0000u;
    return ua | ub;
}
__device__ __forceinline__ float bflo(u32 v) { return __uint_as_float(v << 16); }
__device__ __forceinline__ float bfhi(u32 v) { return __uint_as_float(v & 0xffff0000u); }

// ---------------------------------------------------------------------------
// Kernel 1: softmax attention weights w9[n][9][H][W]
// tile 64x16 (+1 halo), 512 threads, async LDS staging, bf16 x1/x2 in LDS
// ---------------------------------------------------------------------------
__global__ __launch_bounds__(512, 4)
void san_weights(const float* __restrict__ x,
                 const float* __restrict__ w1, const float* __restrict__ b1,
                 const float* __restrict__ w2, const float* __restrict__ b2,
                 const float* __restrict__ cpw,
                 const float* __restrict__ bn1g, const float* __restrict__ bn1b,
                 const float* __restrict__ bn1m, const float* __restrict__ bn1v,
                 const float* __restrict__ wmid,
                 const float* __restrict__ bn2g, const float* __restrict__ bn2b,
                 const float* __restrict__ bn2m, const float* __restrict__ bn2v,
                 const float* __restrict__ wout, const float* __restrict__ bout,
                 float* __restrict__ w9)
{
    __shared__ float stage[8 * NCELLP];   // 38912 B
    __shared__ uint4 x2l[NCELL];          // 19008 B (8 bf16 per cell)
    __shared__ uint4 x1l[TW * TH];        // 16384 B

    const int n = blockIdx.z;
    const int ty = blockIdx.y * TH, tx = blockIdx.x * TW;
    const int tid = threadIdx.x;
    const int wave = tid >> 6, lane = tid & 63;
    const float* xn = x + (size_t)n * CIN * NPIX;

    float acc[3][16];
    #pragma unroll
    for (int o = 0; o < 8; ++o) {
        float b = b1[o];
        acc[0][o] = b; acc[1][o] = b; acc[2][o] = b;
    }
    #pragma unroll
    for (int o = 0; o < 8; ++o) {
        float b = b2[o];
        acc[0][8 + o] = b; acc[1][8 + o] = b; acc[2][8 + o] = b;
    }

    const int cA = tid, cB = tid + 512, cC = tid + 1024;
    const int cCc = (cC < NCELL) ? cC : 0;

    for (int c0 = 0; c0 < 64; c0 += 8) {
        if (c0) __syncthreads();   // previous chunk's LDS reads complete
        // stage 8 channels x halo cells (async, direct-to-LDS)
        for (int t = wave; t < 152; t += 8) {
            int cc = t / 19, r = t - cc * 19;
            int cell = r * 64 + lane;
            if (cell < NCELL) {
                int hy = cell / 66, hx = cell - hy * 66;
                int gy = refl(ty + hy - 1, HH), gx = refl(tx + hx - 1, WW);
                gload_lds4(xn + (size_t)(c0 + cc) * NPIX + gy * WW + gx,
                           &stage[cc * NCELLP + r * 64]);
            }
        }
        __syncthreads();           // staging complete (vmcnt drained)

        float xv[3][8];
        #pragma unroll
        for (int j = 0; j < 8; ++j) {
            xv[0][j] = stage[j * NCELLP + cA];
            xv[1][j] = stage[j * NCELLP + cB];
            xv[2][j] = stage[j * NCELLP + cCc];
        }
        #pragma unroll
        for (int o = 0; o < 16; ++o) {
            const float* wr = (o < 8) ? (w1 + o * CIN + c0) : (w2 + (o - 8) * CIN + c0);
            #pragma unroll
            for (int j = 0; j < 8; ++j) {
                float wj = wr[j];
                acc[0][o] = fmaf(wj, xv[0][j], acc[0][o]);
                acc[1][o] = fmaf(wj, xv[1][j], acc[1][o]);
                acc[2][o] = fmaf(wj, xv[2][j], acc[2][o]);
            }
        }
    }

    // write x1 (interior only) / x2 (all halo cells) to LDS as bf16
    #pragma unroll
    for (int ci = 0; ci < 3; ++ci) {
        int cell = tid + ci * 512;
        if (cell < NCELL) {
            uint4 v2;
            v2.x = bfpack(acc[ci][8],  acc[ci][9]);
            v2.y = bfpack(acc[ci][10], acc[ci][11]);
            v2.z = bfpack(acc[ci][12], acc[ci][13]);
            v2.w = bfpack(acc[ci][14], acc[ci][15]);
            x2l[cell] = v2;
            int hy = cell / 66, hx = cell - hy * 66;
            if (hy >= 1 && hy <= TH && hx >= 1 && hx <= TW) {
                uint4 v1;
                v1.x = bfpack(acc[ci][0], acc[ci][1]);
                v1.y = bfpack(acc[ci][2], acc[ci][3]);
                v1.z = bfpack(acc[ci][4], acc[ci][5]);
                v1.w = bfpack(acc[ci][6], acc[ci][7]);
                x1l[(hy - 1) * TW + (hx - 1)] = v1;
            }
        }
    }
    __syncthreads();

    // fold BN params
    float s1[10], o1[10];
    #pragma unroll
    for (int c = 0; c < 10; ++c) {
        float s = bn1g[c] * rsqrtf(bn1v[c] + 1e-5f);
        s1[c] = s;
        o1[c] = bn1b[c] - bn1m[c] * s;
    }
    float s2[8], o2[8];
    #pragma unroll
    for (int e = 0; e < 8; ++e) {
        float s = bn2g[e] * rsqrtf(bn2v[e] + 1e-5f);
        s2[e] = s;
        o2[e] = bn2b[e] - bn2m[e] * s;
    }
    const float cp00 = cpw[0], cp01 = cpw[1], cp10 = cpw[2], cp11 = cpw[3];
    const float bo = bout[0];

    // MLP + softmax, 2 pixels per thread
    #pragma unroll
    for (int pi = 0; pi < 2; ++pi) {
        int px = tid + pi * 512;
        int py = px >> 6, pxx = px & 63;
        int h = ty + py, w = tx + pxx;
        int cell = (py + 1) * 66 + (pxx + 1);
        uint4 v1 = x1l[px];
        float x1v[8];
        x1v[0] = bflo(v1.x); x1v[1] = bfhi(v1.x);
        x1v[2] = bflo(v1.y); x1v[3] = bfhi(v1.y);
        x1v[4] = bflo(v1.z); x1v[5] = bfhi(v1.z);
        x1v[6] = bflo(v1.w); x1v[7] = bfhi(v1.w);
        float lg[9];
        #pragma unroll
        for (int k = 0; k < 9; ++k) {
            int dy = k / 3 - 1, dx = k % 3 - 1;
            uint4 v2 = x2l[cell + dy * 66 + dx];
            float f[10];
            f[0] = x1v[0] - bflo(v2.x); f[1] = x1v[1] - bfhi(v2.x);
            f[2] = x1v[2] - bflo(v2.y); f[3] = x1v[3] - bfhi(v2.y);
            f[4] = x1v[4] - bflo(v2.z); f[5] = x1v[5] - bfhi(v2.z);
            f[6] = x1v[6] - bflo(v2.w); f[7] = x1v[7] - bfhi(v2.w);
            int hn = refl(h + dy, HH), wn = refl(w + dx, WW);
            float dp0 = (2.0f / 255.0f) * (float)(w - wn);
            float dp1 = (2.0f / 255.0f) * (float)(h - hn);
            f[8] = cp00 * dp0 + cp01 * dp1;
            f[9] = cp10 * dp0 + cp11 * dp1;
            float a[10];
            #pragma unroll
            for (int c = 0; c < 10; ++c)
                a[c] = fmaxf(fmaf(f[c], s1[c], o1[c]), 0.0f);
            float lgk = bo;
            #pragma unroll
            for (int e = 0; e < 8; ++e) {
                float g = 0.0f;
                #pragma unroll
                for (int c = 0; c < 10; ++c) g = fmaf(wmid[e * 10 + c], a[c], g);
                g = fmaxf(fmaf(g, s2[e], o2[e]), 0.0f);
                lgk = fmaf(wout[e], g, lgk);
            }
            lg[k] = lgk;
        }
        float m = lg[0];
        #pragma unroll
        for (int k = 1; k < 9; ++k) m = fmaxf(m, lg[k]);
        float e9[9], ssum = 0.0f;
        #pragma unroll
        for (int k = 0; k < 9; ++k) { e9[k] = __expf(lg[k] - m); ssum += e9[k]; }
        float inv = 1.0f / ssum;
        size_t base = (size_t)n * 9 * NPIX + (size_t)h * WW + w;
        #pragma unroll
        for (int k = 0; k < 9; ++k) w9[base + (size_t)k * NPIX] = e9[k] * inv;
    }
}

// ---------------------------------------------------------------------------
// Kernel 2: s_c = sum_k w_k * x_c[p+dk]; out = W3 @ s + b3
// tile 64x16, 1024 threads (1 px/thread), double-buffered async LDS staging
// ---------------------------------------------------------------------------
__global__ __launch_bounds__(1024, 4)
void san_agg(const float* __restrict__ x, const float* __restrict__ w9,
             const float* __restrict__ w3, const float* __restrict__ b3,
             float* __restrict__ out)
{
    __shared__ float buf[2][16 * NCELLP];  // 2 x 77824 B
    const int n = blockIdx.z;
    const int ty = blockIdx.y * TH, tx = blockIdx.x * TW;
    const int tid = threadIdx.x;
    const int wave = tid >> 6, lane = tid & 63;
    const int pxx = tid & 63, py = tid >> 6;
    const int h = ty + py, w = tx + pxx;
    const float* xn = x + (size_t)n * CIN * NPIX;

    float wk[9];
    {
        size_t wb = (size_t)n * 9 * NPIX + (size_t)h * WW + w;
        #pragma unroll
        for (int k = 0; k < 9; ++k) wk[k] = w9[wb + (size_t)k * NPIX];
    }
    float acc[64];
    #pragma unroll
    for (int o = 0; o < 64; ++o) acc[o] = 0.0f;

    const int cellc = (py + 1) * 66 + (pxx + 1);

    auto stage = [&](int ch0, int b) {
        for (int t = wave; t < 304; t += 16) {
            int cc = t / 19, r = t - cc * 19;
            int cell = r * 64 + lane;
            if (cell < NCELL) {
                int hy = cell / 66, hx = cell - hy * 66;
                int gy = refl(ty + hy - 1, HH), gx = refl(tx + hx - 1, WW);
                gload_lds4(xn + (size_t)(ch0 + cc) * NPIX + gy * WW + gx,
                           &buf[b][cc * NCELLP + r * 64]);
            }
        }
    };

    stage(0, 0);
    for (int kc = 0; kc < 4; ++kc) {
        __syncthreads();                       // chunk kc staged; prior compute done
        if (kc < 3) stage((kc + 1) * 16, (kc + 1) & 1);  // prefetch next chunk
        const float* bp = buf[kc & 1];
        float sv[16];
        #pragma unroll
        for (int cc = 0; cc < 16; ++cc) {
            const float* p = bp + cc * NCELLP + cellc;
            float s = wk[0] * p[-67];
            s = fmaf(wk[1], p[-66], s);
            s = fmaf(wk[2], p[-65], s);
            s = fmaf(wk[3], p[-1],  s);
            s = fmaf(wk[4], p[0],   s);
            s = fmaf(wk[5], p[1],   s);
            s = fmaf(wk[6], p[65],  s);
            s = fmaf(wk[7], p[66],  s);
            s = fmaf(wk[8], p[67],  s);
            sv[cc] = s;
        }
        const int c0 = kc * 16;
        #pragma unroll
        for (int o = 0; o < 64; ++o) {
            const float* wr = w3 + o * CIN + c0;
            #pragma unroll
            for (int cc = 0; cc < 16; ++cc)
                acc[o] = fmaf(wr[cc], sv[cc], acc[o]);
        }
    }
    size_t ob = (size_t)n * CIN * NPIX + (size_t)h * WW + w;
    #pragma unroll
    for (int o = 0; o < 64; ++o)
        out[ob + (size_t)o * NPIX] = acc[o] + b3[o];
}

// ---------------------------------------------------------------------------
extern "C" void kernel_launch(void* const* d_in, const int* in_sizes, int n_in,
                              void* d_out, int out_size, void* d_ws, size_t ws_size,
                              hipStream_t stream) {
    const float* x      = (const float*)d_in[0];
    const float* w1     = (const float*)d_in[1];
    const float* b1     = (const float*)d_in[2];
    const float* w2     = (const float*)d_in[3];
    const float* b2     = (const float*)d_in[4];
    const float* w3     = (const float*)d_in[5];
    const float* b3     = (const float*)d_in[6];
    const float* cpw    = (const float*)d_in[7];
    const float* bn1g   = (const float*)d_in[9];
    const float* bn1b   = (const float*)d_in[10];
    const float* bn1m   = (const float*)d_in[11];
    const float* bn1v   = (const float*)d_in[12];
    const float* wmid   = (const float*)d_in[13];
    const float* bn2g   = (const float*)d_in[14];
    const float* bn2b   = (const float*)d_in[15];
    const float* bn2m   = (const float*)d_in[16];
    const float* bn2v   = (const float*)d_in[17];
    const float* wout   = (const float*)d_in[18];
    const float* bout   = (const float*)d_in[19];
    float* out = (float*)d_out;
    float* w9  = (float*)d_ws;  // 16*9*65536 floats = 37.75 MB

    dim3 grid(WW / TW, HH / TH, 16);
    san_weights<<<grid, 512, 0, stream>>>(x, w1, b1, w2, b2, cpw,
                                          bn1g, bn1b, bn1m, bn1v, wmid,
                                          bn2g, bn2b, bn2m, bn2v, wout, bout, w9);
    san_agg<<<grid, 1024, 0, stream>>>(x, w9, w3, b3, out);
}